// Round 6
// baseline (251.407 us; speedup 1.0000x reference)
//
#include <hip/hip_runtime.h>
#include <hip/hip_bf16.h>
#include <math.h>

#define N_PTS 1024
#define BT    128
typedef unsigned int u32;
typedef __attribute__((ext_vector_type(8))) short short8_t;   // 8 bf16 (4 VGPRs)
typedef __attribute__((ext_vector_type(4))) float f32x4;      // MFMA acc

__device__ __forceinline__ float bfi(u32 bits16) {
    union { u32 u; float f; } v; v.u = bits16 << 16; return v.f;
}
__device__ __forceinline__ unsigned short f2bf(float f) {     // RNE f32->bf16
    union { float f; u32 u; } v; v.f = f;
    return (unsigned short)((v.u + 0x7FFFu + ((v.u >> 16) & 1u)) >> 16);
}
__device__ __forceinline__ float ldf(const void* p, int i, bool bf) {
    return bf ? bfi(((const unsigned short*)p)[i]) : ((const float*)p)[i];
}
__device__ __forceinline__ float2 ldp(const void* pbase, int j, bool bf) {
    if (bf) {
        u32 w = ((const u32*)pbase)[j];
        return make_float2(bfi(w & 0xFFFFu), bfi(w >> 16));
    }
    return ((const float2*)pbase)[j];
}
__device__ __forceinline__ bool detect_bf16(const void* pts, int tid, int* s_flag) {
    if (tid < 64) {
        u32 w = ((const u32*)pts)[tid];
        float v = bfi(w & 0xFFFFu);
        bool ok = (v >= 0.0f) && (v <= 1.0f);
        unsigned long long m = __ballot(ok);
        if (tid == 0) *s_flag = (m == 0xFFFFFFFFFFFFFFFFull) ? 1 : 0;
    }
    __syncthreads();
    return *s_flag != 0;
}
__device__ __forceinline__ bool is_nb(float px, float py, float qx, float qy) {
    float dx = px - qx, dy = py - qy;
    // ref: sqrt_rn(rn(rn(dx*dx)+rn(dy*dy))) < 0.3f  <=>  d2 < 0.09f (ulp-exact)
    float d2 = __fadd_rn(__fmul_rn(dx, dx), __fmul_rn(dy, dy));
    return d2 < 0.09f;
}
__device__ __forceinline__ const void* pts_base(const void* pts, int bt, bool bf) {
    return bf ? (const void*)((const unsigned short*)pts + (size_t)bt * N_PTS * 2)
              : (const void*)((const float*)pts + (size_t)bt * N_PTS * 2);
}
// async global->LDS, 16B per lane (lands at lds_base + lane*16) [m97 pattern]
__device__ __forceinline__ void gload16(const u32* g, u32* l) {
    __builtin_amdgcn_global_load_lds((const __attribute__((address_space(1))) u32*)g,
                                     (__attribute__((address_space(3))) u32*)l, 16, 0, 0);
}

// K1: pair sweep -> adjacency bitmask bm[bt][chunk(32)][row(1024)] + cnt->dinv. Zeros gsum.
__global__ __launch_bounds__(256) void k1_bm(const void* __restrict__ pts,
                                             float* __restrict__ dinv,
                                             float* __restrict__ gsum,
                                             u32* __restrict__ bm) {
    int blk = blockIdx.x, tid = threadIdx.x;
    int bt = blk >> 2, q = blk & 3;
    __shared__ float2 sp[N_PTS];
    __shared__ int s_flag;
    bool bf = detect_bf16(pts, tid, &s_flag);
    const void* pb = pts_base(pts, bt, bf);
    for (int j = tid; j < N_PTS; j += 256) sp[j] = ldp(pb, j, bf);
    if (blk < 32) gsum[blk * 256 + tid] = 0.0f;
    __syncthreads();
    int i = q * 256 + tid;
    float px = sp[i].x, py = sp[i].y;
    const float4* sp4 = (const float4*)sp;
    u32* bmrow = bm + (size_t)bt * 32768 + i;
    int cnt = 0;
    for (int c = 0; c < 32; c++) {
        u32 m = 0;
#pragma unroll
        for (int h = 0; h < 8; h++) {
            float4 s01 = sp4[c * 16 + 2 * h], s23 = sp4[c * 16 + 2 * h + 1];
            if (is_nb(px, py, s01.x, s01.y)) m |= 1u << (4 * h);
            if (is_nb(px, py, s01.z, s01.w)) m |= 1u << (4 * h + 1);
            if (is_nb(px, py, s23.x, s23.y)) m |= 1u << (4 * h + 2);
            if (is_nb(px, py, s23.z, s23.w)) m |= 1u << (4 * h + 3);
        }
        bmrow[c * 1024] = m;
        cnt += __popc(m);
    }
    dinv[bt * N_PTS + i] = 1.0f / sqrtf((float)cnt);
}

// K2: phase A: agg0 rows (bitmask-driven); phase B: x1v bf16 in padded A-operand tile
// layout x1vB[bt][tile(16)][ch(64)][72 shorts] (only [0,64) written; pads unread).
__global__ __launch_bounds__(256) void k2_x1v(const void* __restrict__ pts,
                                              const void* __restrict__ W1,
                                              const void* __restrict__ b1,
                                              const float* __restrict__ dinv,
                                              const u32* __restrict__ bm,
                                              u32* __restrict__ x1vB) {
    int blk = blockIdx.x, tid = threadIdx.x;
    int bt = blk >> 2, q = blk & 3;
    __shared__ float2 sud[N_PTS];   // dinv_j * p_j
    __shared__ float2 sax[256];     // agg0 rows of this block
    __shared__ float  sdl[256];
    __shared__ int s_flag;
    bool bf = detect_bf16(pts, tid, &s_flag);
    const void* pb = pts_base(pts, bt, bf);
    for (int j = tid; j < N_PTS; j += 256) {
        float2 p = ldp(pb, j, bf);
        float d = dinv[bt * N_PTS + j];
        sud[j] = make_float2(d * p.x, d * p.y);
    }
    __syncthreads();
    int i = q * 256 + tid;
    float ax = 0.f, ay = 0.f;
    const u32* bmr = bm + (size_t)bt * 32768 + i;
    for (int c = 0; c < 32; c++) {
        u32 m = bmr[c * 1024];
        const float4* uv = (const float4*)sud + c * 16;
#pragma unroll
        for (int h = 0; h < 16; h++) {
            float4 v = uv[h];
            bool b0 = (m >> (2 * h)) & 1u, b1_ = (m >> (2 * h + 1)) & 1u;
            ax += b0 ? v.x : 0.0f;  ay += b0 ? v.y : 0.0f;
            ax += b1_ ? v.z : 0.0f; ay += b1_ ? v.w : 0.0f;
        }
    }
    float di = dinv[bt * N_PTS + i];
    sax[tid] = make_float2(ax * di, ay * di);
    sdl[tid] = di;
    __syncthreads();
    // phase B: tiles q*4..q*4+4; thread = (ch, wave=jj-quarter)
    int ch = tid & 63, wq = tid >> 6;
    float w0 = ldf(W1, 2 * ch, bf), w1v = ldf(W1, 2 * ch + 1, bf), bb = ldf(b1, ch, bf);
    for (int tt = 0; tt < 4; tt++) {
        u32 ow[8];
#pragma unroll
        for (int k2i = 0; k2i < 8; k2i++) {
            int lj = tt * 64 + wq * 16 + 2 * k2i;
            float2 a0 = sax[lj], a1 = sax[lj + 1];
            float v0 = sdl[lj]     * fmaxf(fmaf(w0, a0.x, fmaf(w1v, a0.y, bb)), 0.0f);
            float v1 = sdl[lj + 1] * fmaxf(fmaf(w0, a1.x, fmaf(w1v, a1.y, bb)), 0.0f);
            ow[k2i] = (u32)f2bf(v0) | ((u32)f2bf(v1) << 16);
        }
        u32* dst = x1vB + ((size_t)(bt * 16 + q * 4 + tt) * 64 + ch) * 36 + wq * 8;
        *(uint4*)dst = make_uint4(ow[0], ow[1], ow[2], ow[3]);
        *(uint4*)(dst + 4) = make_uint4(ow[4], ow[5], ow[6], ow[7]);
    }
}

// K3: D^T = x1v^T @ A (A symmetric 0/1 from bitmask, in-register B-frags);
// epilogue W2 @ (di*D^T) via 2nd MFMA; relu+rowsum -> atomic gsum.
// 512 blocks (bt = blk&127 for XCD locality, rowblk = blk>>7), 256 thr.
__global__ __launch_bounds__(256) void k3_mfma(const void* __restrict__ pts,
                                               const void* __restrict__ W2,
                                               const void* __restrict__ b2,
                                               const float* __restrict__ dinv,
                                               const u32* __restrict__ bm,
                                               const u32* __restrict__ x1vB,
                                               float* __restrict__ gsum) {
    // pool dwords: sbm[0,8192) xf0[8192,10496) xf1[10496,12800) W2B[12800,15104)
    // sdi[15104,15360) sb2[15360,15424). dump overlays [0,9216) post-K-loop.
    __shared__ u32 pool[15424];
    __shared__ int s_flag;
    float* poolf = (float*)pool;
    int tid = threadIdx.x, lane = tid & 63, w = tid >> 6;
    int l15 = lane & 15, quad = lane >> 4;
    int blk = blockIdx.x, bt = blk & 127, rowblk = blk >> 7;
    bool bf = detect_bf16(pts, tid, &s_flag);

    const u32* xg = x1vB + (size_t)bt * 36864;   // 16 tiles * 2304 dw
    for (int it = w; it < 9; it += 4)            // prefetch tile 0 -> xf0
        gload16(xg + it * 256 + lane * 4, pool + 8192 + it * 256 + lane * 4);

    const u32* bg_ = bm + (size_t)bt * 32768 + rowblk * 256;
    for (int idx = tid; idx < 8192; idx += 256) {
        int c = idx >> 8, r = idx & 255;
        pool[idx] = bg_[c * 1024 + r];
    }
    unsigned short* W2B = (unsigned short*)(pool + 12800);
    for (int idx = tid; idx < 4096; idx += 256) {
        int o = idx >> 6, c = idx & 63;
        W2B[o * 72 + c] = f2bf(ldf(W2, idx, bf));
    }
    if (tid < 256) poolf[15104 + tid] = dinv[bt * N_PTS + rowblk * 256 + tid];
    if (tid < 64)  poolf[15360 + tid] = ldf(b2, tid, bf);

    f32x4 acc[4][4];   // [rf(row16-block)][nb(ch16-block)]
#pragma unroll
    for (int rf = 0; rf < 4; rf++)
#pragma unroll
        for (int nb = 0; nb < 4; nb++)
#pragma unroll
            for (int r = 0; r < 4; r++) acc[rf][nb][r] = 0.0f;

    for (int t = 0; t < 16; t++) {
        __syncthreads();   // drains vmcnt -> current buf ready
        if (t + 1 < 16) {
            u32* dst = pool + ((t & 1) ? 8192 : 10496);
            const u32* src = xg + (t + 1) * 2304;
            for (int it = w; it < 9; it += 4)
                gload16(src + it * 256 + lane * 4, dst + it * 256 + lane * 4);
        }
        const unsigned short* xf = (const unsigned short*)(pool + ((t & 1) ? 10496 : 8192));
#pragma unroll
        for (int ks = 0; ks < 2; ks++) {
            short8_t bq[4];
#pragma unroll
            for (int rf = 0; rf < 4; rf++) {
                u32 mw = pool[(2 * t + ks) * 256 + w * 64 + rf * 16 + l15];
                u32 by = (mw >> (quad * 8)) & 0xFFu;
                short8_t v;
#pragma unroll
                for (int i2 = 0; i2 < 8; i2++)
                    v[i2] = (by & (1u << i2)) ? (short)0x3F80 : (short)0;
                bq[rf] = v;
            }
#pragma unroll
            for (int nb = 0; nb < 4; nb++) {
                short8_t af = *(const short8_t*)(xf + (nb * 16 + l15) * 72 + ks * 32 + quad * 8);
#pragma unroll
                for (int rf = 0; rf < 4; rf++)
                    acc[rf][nb] = __builtin_amdgcn_mfma_f32_16x16x32_bf16(af, bq[rf], acc[rf][nb], 0, 0, 0);
            }
        }
    }
    __syncthreads();

    // dump di*D^T as bf16 [256 rows][72 shorts] (pad rows, 2-way-free banks)
    u32* dump = pool;
#pragma unroll
    for (int rf = 0; rf < 4; rf++) {
        int rn = w * 64 + rf * 16 + l15;
        float di = poolf[15104 + rn];
#pragma unroll
        for (int nb = 0; nb < 4; nb++) {
            u32 lo = (u32)f2bf(acc[rf][nb][0] * di) | ((u32)f2bf(acc[rf][nb][1] * di) << 16);
            u32 hi = (u32)f2bf(acc[rf][nb][2] * di) | ((u32)f2bf(acc[rf][nb][3] * di) << 16);
            u32* dst = dump + rn * 36 + nb * 8 + quad * 2;
            dst[0] = lo; dst[1] = hi;
        }
    }
    __syncthreads();
    f32x4 xacc[4][4];  // [ob(o16-block)][rf]
#pragma unroll
    for (int ob = 0; ob < 4; ob++)
#pragma unroll
        for (int rf = 0; rf < 4; rf++)
#pragma unroll
            for (int r = 0; r < 4; r++) xacc[ob][rf][r] = 0.0f;
#pragma unroll
    for (int ks2 = 0; ks2 < 2; ks2++) {
        short8_t b2f[4];
#pragma unroll
        for (int rf = 0; rf < 4; rf++)
            b2f[rf] = *(const short8_t*)((const unsigned short*)dump +
                        (w * 64 + rf * 16 + l15) * 72 + ks2 * 32 + quad * 8);
#pragma unroll
        for (int ob = 0; ob < 4; ob++) {
            short8_t a2 = *(const short8_t*)(W2B + (ob * 16 + l15) * 72 + ks2 * 32 + quad * 8);
#pragma unroll
            for (int rf = 0; rf < 4; rf++)
                xacc[ob][rf] = __builtin_amdgcn_mfma_f32_16x16x32_bf16(a2, b2f[rf], xacc[ob][rf], 0, 0, 0);
        }
    }
#pragma unroll
    for (int ob = 0; ob < 4; ob++) {
#pragma unroll
        for (int r = 0; r < 4; r++) {
            int o = ob * 16 + quad * 4 + r;
            float bb = poolf[15360 + o];
            float s = 0.0f;
#pragma unroll
            for (int rf = 0; rf < 4; rf++) s += fmaxf(xacc[ob][rf][r] + bb, 0.0f);
            s += __shfl_down(s, 8, 16);
            s += __shfl_down(s, 4, 16);
            s += __shfl_down(s, 2, 16);
            s += __shfl_down(s, 1, 16);
            if (l15 == 0) atomicAdd(&gsum[bt * 64 + o], s);
        }
    }
}

// K4: per batch: gm -> Wg matvec -> Wih gi -> GRU over T -> mean_h @ Wf^T + bf. 4 x 384.
__global__ __launch_bounds__(384) void k4_all(const void* __restrict__ pts,
                                              const void* __restrict__ Wg,
                                              const void* __restrict__ bg,
                                              const void* __restrict__ Wih,
                                              const void* __restrict__ Whh,
                                              const void* __restrict__ bih,
                                              const void* __restrict__ bhh,
                                              const void* __restrict__ Wf,
                                              const void* __restrict__ bf_,
                                              const float* __restrict__ gsum,
                                              float* __restrict__ out) {
    int b = blockIdx.x, tid = threadIdx.x;
    __shared__ float s_gi[32 * 384];   // 48 KB
    __shared__ float sWgT[64 * 65];
    __shared__ float s_gm[2048];
    __shared__ float s_x[2048];
    __shared__ float s_gh[384];
    __shared__ float s_h[128];
    __shared__ float s_hsum[128];
    __shared__ int s_flag;
    bool bf = detect_bf16(pts, tid, &s_flag);
    for (int idx = tid; idx < 4096; idx += 384) {
        int o = idx >> 6, k = idx & 63;
        sWgT[k * 65 + o] = ldf(Wg, idx, bf);
    }
    for (int idx = tid; idx < 2048; idx += 384)
        s_gm[idx] = gsum[(size_t)b * 2048 + idx] * (1.0f / 1024.0f);
    if (tid < 128) { s_h[tid] = 0.0f; s_hsum[tid] = 0.0f; }
    __syncthreads();
    for (int idx = tid; idx < 2048; idx += 384) {
        int t = idx >> 6, c = idx & 63;
        float s = ldf(bg, c, bf);
        for (int k = 0; k < 64; k++) s = fmaf(sWgT[k * 65 + c], s_gm[t * 64 + k], s);
        s_x[idx] = s;
    }
    __syncthreads();
    {
        int r = tid;
        float wv[64];
        if (bf) {
#pragma unroll
            for (int k = 0; k < 64; k++) wv[k] = bfi(((const unsigned short*)Wih)[r * 64 + k]);
        } else {
            const float4* wr = (const float4*)Wih + r * 16;
#pragma unroll
            for (int qq = 0; qq < 16; qq++) {
                float4 v = wr[qq];
                wv[4*qq] = v.x; wv[4*qq+1] = v.y; wv[4*qq+2] = v.z; wv[4*qq+3] = v.w;
            }
        }
        float br = ldf(bih, r, bf);
        for (int t = 0; t < 32; t++) {
            float s = br;
#pragma unroll
            for (int k = 0; k < 64; k++) s = fmaf(wv[k], s_x[t * 64 + k], s);
            s_gi[t * 384 + r] = s;
        }
    }
    float wh[128];
    if (bf) {
#pragma unroll
        for (int k = 0; k < 128; k++) wh[k] = bfi(((const unsigned short*)Whh)[tid * 128 + k]);
    } else {
        const float4* wr = (const float4*)Whh + tid * 32;
#pragma unroll
        for (int qq = 0; qq < 32; qq++) {
            float4 v = wr[qq];
            wh[4*qq] = v.x; wh[4*qq+1] = v.y; wh[4*qq+2] = v.z; wh[4*qq+3] = v.w;
        }
    }
    float bhr = ldf(bhh, tid, bf);
    __syncthreads();
    for (int t = 0; t < 32; t++) {
        float s = bhr;
#pragma unroll
        for (int k = 0; k < 128; k++) s = fmaf(wh[k], s_h[k], s);
        s_gh[tid] = s;
        __syncthreads();
        if (tid < 128) {
            int c = tid;
            float gr = s_gi[t * 384 + c]       + s_gh[c];
            float gz = s_gi[t * 384 + 128 + c] + s_gh[128 + c];
            float gn = s_gi[t * 384 + 256 + c];
            float hn = s_gh[256 + c];
            float r = 1.0f / (1.0f + expf(-gr));
            float z = 1.0f / (1.0f + expf(-gz));
            float n = tanhf(fmaf(r, hn, gn));
            float hnew = (1.0f - z) * n + z * s_h[c];
            s_h[c] = hnew;
            s_hsum[c] += hnew;
        }
        __syncthreads();
    }
    if (tid < 2) {
        float s = ldf(bf_, tid, bf);
        for (int k = 0; k < 128; k++)
            s = fmaf(ldf(Wf, tid * 128 + k, bf), s_hsum[k] * (1.0f / 32.0f), s);
        out[b * 2 + tid] = s;   // f32 output (verified R4)
    }
}

extern "C" void kernel_launch(void* const* d_in, const int* in_sizes, int n_in,
                              void* d_out, int out_size, void* d_ws, size_t ws_size,
                              hipStream_t stream) {
    const void* pts = d_in[0];
    const void* W1  = d_in[1];
    const void* b1  = d_in[2];
    const void* W2  = d_in[3];
    const void* b2  = d_in[4];
    const void* Wg  = d_in[5];
    const void* bg  = d_in[6];
    const void* Wih = d_in[7];
    const void* Whh = d_in[8];
    const void* bih = d_in[9];
    const void* bhh = d_in[10];
    const void* Wf  = d_in[11];
    const void* bf_ = d_in[12];

    // ws: dinv 512K | gsum 32K | bm 16M | x1vB 18M  (~34.5 MB)
    float* dinv = (float*)d_ws;
    float* gsum = dinv + (size_t)BT * N_PTS;
    u32*   bm   = (u32*)(gsum + BT * 64);
    u32*   x1vB = bm + (size_t)BT * 32768;

    k1_bm  <<<512, 256, 0, stream>>>(pts, dinv, gsum, bm);
    k2_x1v <<<512, 256, 0, stream>>>(pts, W1, b1, dinv, bm, x1vB);
    k3_mfma<<<512, 256, 0, stream>>>(pts, W2, b2, dinv, bm, x1vB, gsum);
    k4_all <<<4, 384, 0, stream>>>(pts, Wg, bg, Wih, Whh, bih, bhh, Wf, bf_,
                                   gsum, (float*)d_out);
}

// Round 7
// 242.874 us; speedup vs baseline: 1.0351x; 1.0351x over previous
//
#include <hip/hip_runtime.h>
#include <hip/hip_bf16.h>
#include <math.h>

#define N_PTS 1024
#define BT    128
typedef unsigned int u32;
typedef __attribute__((ext_vector_type(8))) short short8_t;   // 8 bf16 (4 VGPRs)
typedef __attribute__((ext_vector_type(4))) float f32x4;      // MFMA acc

__device__ __forceinline__ float bfi(u32 bits16) {
    union { u32 u; float f; } v; v.u = bits16 << 16; return v.f;
}
__device__ __forceinline__ unsigned short f2bf(float f) {     // RNE f32->bf16
    union { float f; u32 u; } v; v.f = f;
    return (unsigned short)((v.u + 0x7FFFu + ((v.u >> 16) & 1u)) >> 16);
}
__device__ __forceinline__ float ldf(const void* p, int i, bool bf) {
    return bf ? bfi(((const unsigned short*)p)[i]) : ((const float*)p)[i];
}
__device__ __forceinline__ float2 ldp(const void* pbase, int j, bool bf) {
    if (bf) {
        u32 w = ((const u32*)pbase)[j];
        return make_float2(bfi(w & 0xFFFFu), bfi(w >> 16));
    }
    return ((const float2*)pbase)[j];
}
__device__ __forceinline__ bool detect_bf16(const void* pts, int tid, int* s_flag) {
    if (tid < 64) {
        u32 w = ((const u32*)pts)[tid];
        float v = bfi(w & 0xFFFFu);
        bool ok = (v >= 0.0f) && (v <= 1.0f);
        unsigned long long m = __ballot(ok);
        if (tid == 0) *s_flag = (m == 0xFFFFFFFFFFFFFFFFull) ? 1 : 0;
    }
    __syncthreads();
    return *s_flag != 0;
}
__device__ __forceinline__ bool is_nb(float px, float py, float qx, float qy) {
    float dx = px - qx, dy = py - qy;
    // ref: sqrt_rn(rn(rn(dx*dx)+rn(dy*dy))) < 0.3f  <=>  d2 < 0.09f (ulp-exact)
    float d2 = __fadd_rn(__fmul_rn(dx, dx), __fmul_rn(dy, dy));
    return d2 < 0.09f;
}
__device__ __forceinline__ const void* pts_base(const void* pts, int bt, bool bf) {
    return bf ? (const void*)((const unsigned short*)pts + (size_t)bt * N_PTS * 2)
              : (const void*)((const float*)pts + (size_t)bt * N_PTS * 2);
}
// async global->LDS, 16B per lane (lands at lds_base + lane*16) [m97 pattern]
__device__ __forceinline__ void gload16(const u32* g, u32* l) {
    __builtin_amdgcn_global_load_lds((const __attribute__((address_space(1))) u32*)g,
                                     (__attribute__((address_space(3))) u32*)l, 16, 0, 0);
}

// K1: pair sweep -> adjacency bitmask bm[bt][chunk(32)][row(1024)] + cnt->dinv. Zeros gsum.
__global__ __launch_bounds__(256) void k1_bm(const void* __restrict__ pts,
                                             float* __restrict__ dinv,
                                             float* __restrict__ gsum,
                                             u32* __restrict__ bm) {
    int blk = blockIdx.x, tid = threadIdx.x;
    int bt = blk >> 2, q = blk & 3;
    __shared__ float2 sp[N_PTS];
    __shared__ int s_flag;
    bool bf = detect_bf16(pts, tid, &s_flag);
    const void* pb = pts_base(pts, bt, bf);
    for (int j = tid; j < N_PTS; j += 256) sp[j] = ldp(pb, j, bf);
    if (blk < 32) gsum[blk * 256 + tid] = 0.0f;
    __syncthreads();
    int i = q * 256 + tid;
    float px = sp[i].x, py = sp[i].y;
    const float4* sp4 = (const float4*)sp;
    u32* bmrow = bm + (size_t)bt * 32768 + i;
    int cnt = 0;
    for (int c = 0; c < 32; c++) {
        u32 m = 0;
#pragma unroll
        for (int h = 0; h < 8; h++) {
            float4 s01 = sp4[c * 16 + 2 * h], s23 = sp4[c * 16 + 2 * h + 1];
            if (is_nb(px, py, s01.x, s01.y)) m |= 1u << (4 * h);
            if (is_nb(px, py, s01.z, s01.w)) m |= 1u << (4 * h + 1);
            if (is_nb(px, py, s23.x, s23.y)) m |= 1u << (4 * h + 2);
            if (is_nb(px, py, s23.z, s23.w)) m |= 1u << (4 * h + 3);
        }
        bmrow[c * 1024] = m;
        cnt += __popc(m);
    }
    dinv[bt * N_PTS + i] = 1.0f / sqrtf((float)cnt);
}

// K2: phase A: agg0 rows (bitmask-driven); phase B: x1v bf16 in padded A-operand tile
// layout x1vB[bt][tile(16)][ch(64)][72 shorts] (only [0,64) written; pads unread).
__global__ __launch_bounds__(256) void k2_x1v(const void* __restrict__ pts,
                                              const void* __restrict__ W1,
                                              const void* __restrict__ b1,
                                              const float* __restrict__ dinv,
                                              const u32* __restrict__ bm,
                                              u32* __restrict__ x1vB) {
    int blk = blockIdx.x, tid = threadIdx.x;
    int bt = blk >> 2, q = blk & 3;
    __shared__ float2 sud[N_PTS];   // dinv_j * p_j
    __shared__ float2 sax[256];     // agg0 rows of this block
    __shared__ float  sdl[256];
    __shared__ int s_flag;
    bool bf = detect_bf16(pts, tid, &s_flag);
    const void* pb = pts_base(pts, bt, bf);
    for (int j = tid; j < N_PTS; j += 256) {
        float2 p = ldp(pb, j, bf);
        float d = dinv[bt * N_PTS + j];
        sud[j] = make_float2(d * p.x, d * p.y);
    }
    __syncthreads();
    int i = q * 256 + tid;
    float ax = 0.f, ay = 0.f;
    const u32* bmr = bm + (size_t)bt * 32768 + i;
    for (int c = 0; c < 32; c++) {
        u32 m = bmr[c * 1024];
        const float4* uv = (const float4*)sud + c * 16;
#pragma unroll
        for (int h = 0; h < 16; h++) {
            float4 v = uv[h];
            bool b0 = (m >> (2 * h)) & 1u, b1_ = (m >> (2 * h + 1)) & 1u;
            ax += b0 ? v.x : 0.0f;  ay += b0 ? v.y : 0.0f;
            ax += b1_ ? v.z : 0.0f; ay += b1_ ? v.w : 0.0f;
        }
    }
    float di = dinv[bt * N_PTS + i];
    sax[tid] = make_float2(ax * di, ay * di);
    sdl[tid] = di;
    __syncthreads();
    // phase B: tiles q*4..q*4+4; thread = (ch, wave=jj-quarter)
    int ch = tid & 63, wq = tid >> 6;
    float w0 = ldf(W1, 2 * ch, bf), w1v = ldf(W1, 2 * ch + 1, bf), bb = ldf(b1, ch, bf);
    for (int tt = 0; tt < 4; tt++) {
        u32 ow[8];
#pragma unroll
        for (int k2i = 0; k2i < 8; k2i++) {
            int lj = tt * 64 + wq * 16 + 2 * k2i;
            float2 a0 = sax[lj], a1 = sax[lj + 1];
            float v0 = sdl[lj]     * fmaxf(fmaf(w0, a0.x, fmaf(w1v, a0.y, bb)), 0.0f);
            float v1 = sdl[lj + 1] * fmaxf(fmaf(w0, a1.x, fmaf(w1v, a1.y, bb)), 0.0f);
            ow[k2i] = (u32)f2bf(v0) | ((u32)f2bf(v1) << 16);
        }
        u32* dst = x1vB + ((size_t)(bt * 16 + q * 4 + tt) * 64 + ch) * 36 + wq * 8;
        *(uint4*)dst = make_uint4(ow[0], ow[1], ow[2], ow[3]);
        *(uint4*)(dst + 4) = make_uint4(ow[4], ow[5], ow[6], ow[7]);
    }
}

// K3: D^T = x1v^T @ A (A symmetric 0/1 from bitmask, in-register B-frags);
// epilogue W2 @ (di*D^T) via 2nd MFMA; relu+rowsum -> atomic gsum.
// 512 blocks (bt = blk&127 for XCD locality, rowblk = blk>>7), 256 thr.
__global__ __launch_bounds__(256) void k3_mfma(const void* __restrict__ pts,
                                               const void* __restrict__ W2,
                                               const void* __restrict__ b2,
                                               const float* __restrict__ dinv,
                                               const u32* __restrict__ bm,
                                               const u32* __restrict__ x1vB,
                                               float* __restrict__ gsum) {
    // pool dwords: sbm[0,8192) xf0[8192,10496) xf1[10496,12800) W2B[12800,15104)
    // sdi[15104,15360) sb2[15360,15424). dump overlays [0,9216) post-K-loop.
    __shared__ u32 pool[15424];
    __shared__ int s_flag;
    float* poolf = (float*)pool;
    int tid = threadIdx.x, lane = tid & 63, w = tid >> 6;
    int l15 = lane & 15, quad = lane >> 4;
    int blk = blockIdx.x, bt = blk & 127, rowblk = blk >> 7;
    bool bf = detect_bf16(pts, tid, &s_flag);

    const u32* xg = x1vB + (size_t)bt * 36864;   // 16 tiles * 2304 dw
    for (int it = w; it < 9; it += 4)            // prefetch tile 0 -> xf0
        gload16(xg + it * 256 + lane * 4, pool + 8192 + it * 256 + lane * 4);

    const u32* bg_ = bm + (size_t)bt * 32768 + rowblk * 256;
    for (int idx = tid; idx < 8192; idx += 256) {
        int c = idx >> 8, r = idx & 255;
        pool[idx] = bg_[c * 1024 + r];
    }
    unsigned short* W2B = (unsigned short*)(pool + 12800);
    for (int idx = tid; idx < 4096; idx += 256) {
        int o = idx >> 6, c = idx & 63;
        W2B[o * 72 + c] = f2bf(ldf(W2, idx, bf));
    }
    if (tid < 256) poolf[15104 + tid] = dinv[bt * N_PTS + rowblk * 256 + tid];
    if (tid < 64)  poolf[15360 + tid] = ldf(b2, tid, bf);

    f32x4 acc[4][4];   // [rf(row16-block)][nb(ch16-block)]
#pragma unroll
    for (int rf = 0; rf < 4; rf++)
#pragma unroll
        for (int nb = 0; nb < 4; nb++)
#pragma unroll
            for (int r = 0; r < 4; r++) acc[rf][nb][r] = 0.0f;

    for (int t = 0; t < 16; t++) {
        __syncthreads();   // drains vmcnt -> current buf ready
        if (t + 1 < 16) {
            u32* dst = pool + ((t & 1) ? 8192 : 10496);
            const u32* src = xg + (t + 1) * 2304;
            for (int it = w; it < 9; it += 4)
                gload16(src + it * 256 + lane * 4, dst + it * 256 + lane * 4);
        }
        const unsigned short* xf = (const unsigned short*)(pool + ((t & 1) ? 10496 : 8192));
#pragma unroll
        for (int ks = 0; ks < 2; ks++) {
            short8_t bq[4];
#pragma unroll
            for (int rf = 0; rf < 4; rf++) {
                u32 mw = pool[(2 * t + ks) * 256 + w * 64 + rf * 16 + l15];
                u32 by = (mw >> (quad * 8)) & 0xFFu;
                short8_t v;
#pragma unroll
                for (int i2 = 0; i2 < 8; i2++)
                    v[i2] = (by & (1u << i2)) ? (short)0x3F80 : (short)0;
                bq[rf] = v;
            }
#pragma unroll
            for (int nb = 0; nb < 4; nb++) {
                short8_t af = *(const short8_t*)(xf + (nb * 16 + l15) * 72 + ks * 32 + quad * 8);
#pragma unroll
                for (int rf = 0; rf < 4; rf++)
                    acc[rf][nb] = __builtin_amdgcn_mfma_f32_16x16x32_bf16(af, bq[rf], acc[rf][nb], 0, 0, 0);
            }
        }
    }
    __syncthreads();

    // dump di*D^T as bf16 [256 rows][72 shorts] (pad rows, 2-way-free banks)
    u32* dump = pool;
#pragma unroll
    for (int rf = 0; rf < 4; rf++) {
        int rn = w * 64 + rf * 16 + l15;
        float di = poolf[15104 + rn];
#pragma unroll
        for (int nb = 0; nb < 4; nb++) {
            u32 lo = (u32)f2bf(acc[rf][nb][0] * di) | ((u32)f2bf(acc[rf][nb][1] * di) << 16);
            u32 hi = (u32)f2bf(acc[rf][nb][2] * di) | ((u32)f2bf(acc[rf][nb][3] * di) << 16);
            u32* dst = dump + rn * 36 + nb * 8 + quad * 2;
            dst[0] = lo; dst[1] = hi;
        }
    }
    __syncthreads();
    f32x4 xacc[4][4];  // [ob(o16-block)][rf]
#pragma unroll
    for (int ob = 0; ob < 4; ob++)
#pragma unroll
        for (int rf = 0; rf < 4; rf++)
#pragma unroll
            for (int r = 0; r < 4; r++) xacc[ob][rf][r] = 0.0f;
#pragma unroll
    for (int ks2 = 0; ks2 < 2; ks2++) {
        short8_t b2f[4];
#pragma unroll
        for (int rf = 0; rf < 4; rf++)
            b2f[rf] = *(const short8_t*)((const unsigned short*)dump +
                        (w * 64 + rf * 16 + l15) * 72 + ks2 * 32 + quad * 8);
#pragma unroll
        for (int ob = 0; ob < 4; ob++) {
            short8_t a2 = *(const short8_t*)(W2B + (ob * 16 + l15) * 72 + ks2 * 32 + quad * 8);
#pragma unroll
            for (int rf = 0; rf < 4; rf++)
                xacc[ob][rf] = __builtin_amdgcn_mfma_f32_16x16x32_bf16(a2, b2f[rf], xacc[ob][rf], 0, 0, 0);
        }
    }
#pragma unroll
    for (int ob = 0; ob < 4; ob++) {
#pragma unroll
        for (int r = 0; r < 4; r++) {
            int o = ob * 16 + quad * 4 + r;
            float bb = poolf[15360 + o];
            float s = 0.0f;
#pragma unroll
            for (int rf = 0; rf < 4; rf++) s += fmaxf(xacc[ob][rf][r] + bb, 0.0f);
            s += __shfl_down(s, 8, 16);
            s += __shfl_down(s, 4, 16);
            s += __shfl_down(s, 2, 16);
            s += __shfl_down(s, 1, 16);
            if (l15 == 0) atomicAdd(&gsum[bt * 64 + o], s);
        }
    }
}

// K4: per batch, 768 threads (2 threads per GRU row; max 64-f32 per-thread arrays
// -> no scratch spill, unlike R6's wh[128] @ VGPR_Count=96).
__global__ __launch_bounds__(768, 1) void k4_all(const void* __restrict__ pts,
                                                 const void* __restrict__ Wg,
                                                 const void* __restrict__ bg,
                                                 const void* __restrict__ Wih,
                                                 const void* __restrict__ Whh,
                                                 const void* __restrict__ bih,
                                                 const void* __restrict__ bhh,
                                                 const void* __restrict__ Wf,
                                                 const void* __restrict__ bf_,
                                                 const float* __restrict__ gsum,
                                                 float* __restrict__ out) {
    int b = blockIdx.x, tid = threadIdx.x;
    __shared__ float s_gi[32 * 384];   // 48 KB
    __shared__ float sWgT[64 * 65];    // 16.25 KB
    __shared__ float s_gm[2048];       // 8 KB
    __shared__ float s_x[2048];        // 8 KB
    __shared__ float s_part[768];      // 3 KB
    __shared__ float s_h[128];
    __shared__ int s_flag;
    bool bf = detect_bf16(pts, tid, &s_flag);
    for (int idx = tid; idx < 4096; idx += 768) {
        int o = idx >> 6, k = idx & 63;
        sWgT[k * 65 + o] = ldf(Wg, idx, bf);
    }
    for (int idx = tid; idx < 2048; idx += 768)
        s_gm[idx] = gsum[(size_t)b * 2048 + idx] * (1.0f / 1024.0f);
    if (tid < 128) s_h[tid] = 0.0f;
    __syncthreads();
    // x[t][c] = bg[c] + Wg[c,:] @ gm[t,:]   (4-way split chains)
    for (int idx = tid; idx < 2048; idx += 768) {
        int t = idx >> 6, c = idx & 63;
        float s0 = ldf(bg, c, bf), s1 = 0.f, s2 = 0.f, s3 = 0.f;
        const float* gm = s_gm + t * 64;
#pragma unroll
        for (int k = 0; k < 64; k += 4) {
            s0 = fmaf(sWgT[k * 65 + c],       gm[k],     s0);
            s1 = fmaf(sWgT[(k + 1) * 65 + c], gm[k + 1], s1);
            s2 = fmaf(sWgT[(k + 2) * 65 + c], gm[k + 2], s2);
            s3 = fmaf(sWgT[(k + 3) * 65 + c], gm[k + 3], s3);
        }
        s_x[idx] = (s0 + s1) + (s2 + s3);
    }
    __syncthreads();
    int hi = (tid >= 384) ? 1 : 0;
    int r = tid - hi * 384;
    // gi[t][r] for t ≡ hi (mod 2); Wih row r in regs (64 f32)
    {
        float wv[64];
        if (bf) {
#pragma unroll
            for (int k = 0; k < 64; k++) wv[k] = bfi(((const unsigned short*)Wih)[r * 64 + k]);
        } else {
            const float4* wr = (const float4*)Wih + r * 16;
#pragma unroll
            for (int qq = 0; qq < 16; qq++) {
                float4 v = wr[qq];
                wv[4*qq] = v.x; wv[4*qq+1] = v.y; wv[4*qq+2] = v.z; wv[4*qq+3] = v.w;
            }
        }
        float br = ldf(bih, r, bf);
        for (int t = hi; t < 32; t += 2) {
            float s0 = br, s1 = 0.f, s2 = 0.f, s3 = 0.f;
            const float4* x4 = (const float4*)(s_x + t * 64);
#pragma unroll
            for (int qq = 0; qq < 16; qq++) {
                float4 v = x4[qq];
                s0 = fmaf(wv[4*qq],   v.x, s0);
                s1 = fmaf(wv[4*qq+1], v.y, s1);
                s2 = fmaf(wv[4*qq+2], v.z, s2);
                s3 = fmaf(wv[4*qq+3], v.w, s3);
            }
            s_gi[t * 384 + r] = (s0 + s1) + (s2 + s3);
        }
    }
    // Whh half-row in regs (64 f32)
    float wh2[64];
    {
        int koff = hi * 64;
        if (bf) {
#pragma unroll
            for (int k = 0; k < 64; k++)
                wh2[k] = bfi(((const unsigned short*)Whh)[r * 128 + koff + k]);
        } else {
            const float4* wr = (const float4*)Whh + (r * 128 + koff) / 4;
#pragma unroll
            for (int qq = 0; qq < 16; qq++) {
                float4 v = wr[qq];
                wh2[4*qq] = v.x; wh2[4*qq+1] = v.y; wh2[4*qq+2] = v.z; wh2[4*qq+3] = v.w;
            }
        }
    }
    float bhr = hi ? 0.0f : ldf(bhh, r, bf);
    float h_reg = 0.0f, hsum = 0.0f;
    __syncthreads();

    for (int t = 0; t < 32; t++) {
        const float4* h4 = (const float4*)(s_h + hi * 64);   // wave-uniform base
        float s0 = bhr, s1 = 0.f, s2 = 0.f, s3 = 0.f;
#pragma unroll
        for (int qq = 0; qq < 16; qq++) {
            float4 hv = h4[qq];
            s0 = fmaf(wh2[4*qq],   hv.x, s0);
            s1 = fmaf(wh2[4*qq+1], hv.y, s1);
            s2 = fmaf(wh2[4*qq+2], hv.z, s2);
            s3 = fmaf(wh2[4*qq+3], hv.w, s3);
        }
        s_part[tid] = (s0 + s1) + (s2 + s3);
        __syncthreads();
        if (tid < 128) {
            int c = tid;
            float gr = s_gi[t * 384 + c]       + s_part[c]       + s_part[384 + c];
            float gz = s_gi[t * 384 + 128 + c] + s_part[128 + c] + s_part[512 + c];
            float gn = s_gi[t * 384 + 256 + c];
            float hn = s_part[256 + c] + s_part[640 + c];
            float rr = 1.0f / (1.0f + expf(-gr));
            float z  = 1.0f / (1.0f + expf(-gz));
            float n  = tanhf(fmaf(rr, hn, gn));
            float hnew = (1.0f - z) * n + z * h_reg;
            h_reg = hnew; hsum += hnew; s_h[c] = hnew;
        }
        __syncthreads();
    }
    if (tid < 128) {
        float hm = hsum * (1.0f / 32.0f);
        s_part[tid]       = ldf(Wf, tid, bf) * hm;
        s_part[128 + tid] = ldf(Wf, 128 + tid, bf) * hm;
    }
    __syncthreads();
    if (tid < 2) {
        float s = ldf(bf_, tid, bf);
        for (int k = 0; k < 128; k++) s += s_part[tid * 128 + k];
        out[b * 2 + tid] = s;   // f32 output (verified R4)
    }
}

extern "C" void kernel_launch(void* const* d_in, const int* in_sizes, int n_in,
                              void* d_out, int out_size, void* d_ws, size_t ws_size,
                              hipStream_t stream) {
    const void* pts = d_in[0];
    const void* W1  = d_in[1];
    const void* b1  = d_in[2];
    const void* W2  = d_in[3];
    const void* b2  = d_in[4];
    const void* Wg  = d_in[5];
    const void* bg  = d_in[6];
    const void* Wih = d_in[7];
    const void* Whh = d_in[8];
    const void* bih = d_in[9];
    const void* bhh = d_in[10];
    const void* Wf  = d_in[11];
    const void* bf_ = d_in[12];

    // ws: dinv 512K | gsum 32K | bm 16M | x1vB 18M  (~34.5 MB)
    float* dinv = (float*)d_ws;
    float* gsum = dinv + (size_t)BT * N_PTS;
    u32*   bm   = (u32*)(gsum + BT * 64);
    u32*   x1vB = bm + (size_t)BT * 32768;

    k1_bm  <<<512, 256, 0, stream>>>(pts, dinv, gsum, bm);
    k2_x1v <<<512, 256, 0, stream>>>(pts, W1, b1, dinv, bm, x1vB);
    k3_mfma<<<512, 256, 0, stream>>>(pts, W2, b2, dinv, bm, x1vB, gsum);
    k4_all <<<4, 768, 0, stream>>>(pts, Wg, bg, Wih, Whh, bih, bhh, Wf, bf_,
                                   gsum, (float*)d_out);
}

// Round 8
// 238.467 us; speedup vs baseline: 1.0543x; 1.0185x over previous
//
#include <hip/hip_runtime.h>
#include <hip/hip_bf16.h>
#include <math.h>

#define N_PTS 1024
#define BT    128
typedef unsigned int u32;
typedef __attribute__((ext_vector_type(8))) short short8_t;   // 8 bf16 (4 VGPRs)
typedef __attribute__((ext_vector_type(4))) float f32x4;      // MFMA acc

__device__ __forceinline__ float bfi(u32 bits16) {
    union { u32 u; float f; } v; v.u = bits16 << 16; return v.f;
}
__device__ __forceinline__ unsigned short f2bf(float f) {     // RNE f32->bf16
    union { float f; u32 u; } v; v.f = f;
    return (unsigned short)((v.u + 0x7FFFu + ((v.u >> 16) & 1u)) >> 16);
}
__device__ __forceinline__ float ldf(const void* p, int i, bool bf) {
    return bf ? bfi(((const unsigned short*)p)[i]) : ((const float*)p)[i];
}
__device__ __forceinline__ float2 ldp(const void* pbase, int j, bool bf) {
    if (bf) {
        u32 w = ((const u32*)pbase)[j];
        return make_float2(bfi(w & 0xFFFFu), bfi(w >> 16));
    }
    return ((const float2*)pbase)[j];
}
__device__ __forceinline__ bool detect_bf16(const void* pts, int tid, int* s_flag) {
    if (tid < 64) {
        u32 w = ((const u32*)pts)[tid];
        float v = bfi(w & 0xFFFFu);
        bool ok = (v >= 0.0f) && (v <= 1.0f);
        unsigned long long m = __ballot(ok);
        if (tid == 0) *s_flag = (m == 0xFFFFFFFFFFFFFFFFull) ? 1 : 0;
    }
    __syncthreads();
    return *s_flag != 0;
}
__device__ __forceinline__ bool is_nb(float px, float py, float qx, float qy) {
    float dx = px - qx, dy = py - qy;
    // ref: sqrt_rn(rn(rn(dx*dx)+rn(dy*dy))) < 0.3f  <=>  d2 < 0.09f (ulp-exact)
    float d2 = __fadd_rn(__fmul_rn(dx, dx), __fmul_rn(dy, dy));
    return d2 < 0.09f;
}
__device__ __forceinline__ const void* pts_base(const void* pts, int bt, bool bf) {
    return bf ? (const void*)((const unsigned short*)pts + (size_t)bt * N_PTS * 2)
              : (const void*)((const float*)pts + (size_t)bt * N_PTS * 2);
}
// async global->LDS, 16B per lane (lands at lds_base + lane*16) [m97 pattern]
__device__ __forceinline__ void gload16(const u32* g, u32* l) {
    __builtin_amdgcn_global_load_lds((const __attribute__((address_space(1))) u32*)g,
                                     (__attribute__((address_space(3))) u32*)l, 16, 0, 0);
}
// wave-uniform broadcast of lane `i` (compile-time) via v_readlane (VALU, not DS pipe)
__device__ __forceinline__ float rdlane(float v, int i) {
    return __int_as_float(__builtin_amdgcn_readlane(__float_as_int(v), i));
}

// K1: pair sweep -> adjacency bitmask bm[bt][chunk(32)][row(1024)] + cnt->dinv. Zeros gsum.
__global__ __launch_bounds__(256) void k1_bm(const void* __restrict__ pts,
                                             float* __restrict__ dinv,
                                             float* __restrict__ gsum,
                                             u32* __restrict__ bm) {
    int blk = blockIdx.x, tid = threadIdx.x;
    int bt = blk >> 2, q = blk & 3;
    __shared__ float2 sp[N_PTS];
    __shared__ int s_flag;
    bool bf = detect_bf16(pts, tid, &s_flag);
    const void* pb = pts_base(pts, bt, bf);
    for (int j = tid; j < N_PTS; j += 256) sp[j] = ldp(pb, j, bf);
    if (blk < 32) gsum[blk * 256 + tid] = 0.0f;
    __syncthreads();
    int i = q * 256 + tid;
    float px = sp[i].x, py = sp[i].y;
    const float4* sp4 = (const float4*)sp;
    u32* bmrow = bm + (size_t)bt * 32768 + i;
    int cnt = 0;
    for (int c = 0; c < 32; c++) {
        u32 m = 0;
#pragma unroll
        for (int h = 0; h < 8; h++) {
            float4 s01 = sp4[c * 16 + 2 * h], s23 = sp4[c * 16 + 2 * h + 1];
            if (is_nb(px, py, s01.x, s01.y)) m |= 1u << (4 * h);
            if (is_nb(px, py, s01.z, s01.w)) m |= 1u << (4 * h + 1);
            if (is_nb(px, py, s23.x, s23.y)) m |= 1u << (4 * h + 2);
            if (is_nb(px, py, s23.z, s23.w)) m |= 1u << (4 * h + 3);
        }
        bmrow[c * 1024] = m;
        cnt += __popc(m);
    }
    dinv[bt * N_PTS + i] = 1.0f / sqrtf((float)cnt);
}

// K2: phase A: agg0 rows (bitmask-driven); phase B: x1v bf16 in padded A-operand tile
// layout x1vB[bt][tile(16)][ch(64)][72 shorts] (only [0,64) written; pads unread).
__global__ __launch_bounds__(256) void k2_x1v(const void* __restrict__ pts,
                                              const void* __restrict__ W1,
                                              const void* __restrict__ b1,
                                              const float* __restrict__ dinv,
                                              const u32* __restrict__ bm,
                                              u32* __restrict__ x1vB) {
    int blk = blockIdx.x, tid = threadIdx.x;
    int bt = blk >> 2, q = blk & 3;
    __shared__ float2 sud[N_PTS];   // dinv_j * p_j
    __shared__ float2 sax[256];     // agg0 rows of this block
    __shared__ float  sdl[256];
    __shared__ int s_flag;
    bool bf = detect_bf16(pts, tid, &s_flag);
    const void* pb = pts_base(pts, bt, bf);
    for (int j = tid; j < N_PTS; j += 256) {
        float2 p = ldp(pb, j, bf);
        float d = dinv[bt * N_PTS + j];
        sud[j] = make_float2(d * p.x, d * p.y);
    }
    __syncthreads();
    int i = q * 256 + tid;
    float ax = 0.f, ay = 0.f;
    const u32* bmr = bm + (size_t)bt * 32768 + i;
    for (int c = 0; c < 32; c++) {
        u32 m = bmr[c * 1024];
        const float4* uv = (const float4*)sud + c * 16;
#pragma unroll
        for (int h = 0; h < 16; h++) {
            float4 v = uv[h];
            bool b0 = (m >> (2 * h)) & 1u, b1_ = (m >> (2 * h + 1)) & 1u;
            ax += b0 ? v.x : 0.0f;  ay += b0 ? v.y : 0.0f;
            ax += b1_ ? v.z : 0.0f; ay += b1_ ? v.w : 0.0f;
        }
    }
    float di = dinv[bt * N_PTS + i];
    sax[tid] = make_float2(ax * di, ay * di);
    sdl[tid] = di;
    __syncthreads();
    // phase B: tiles q*4..q*4+4; thread = (ch, wave=jj-quarter)
    int ch = tid & 63, wq = tid >> 6;
    float w0 = ldf(W1, 2 * ch, bf), w1v = ldf(W1, 2 * ch + 1, bf), bb = ldf(b1, ch, bf);
    for (int tt = 0; tt < 4; tt++) {
        u32 ow[8];
#pragma unroll
        for (int k2i = 0; k2i < 8; k2i++) {
            int lj = tt * 64 + wq * 16 + 2 * k2i;
            float2 a0 = sax[lj], a1 = sax[lj + 1];
            float v0 = sdl[lj]     * fmaxf(fmaf(w0, a0.x, fmaf(w1v, a0.y, bb)), 0.0f);
            float v1 = sdl[lj + 1] * fmaxf(fmaf(w0, a1.x, fmaf(w1v, a1.y, bb)), 0.0f);
            ow[k2i] = (u32)f2bf(v0) | ((u32)f2bf(v1) << 16);
        }
        u32* dst = x1vB + ((size_t)(bt * 16 + q * 4 + tt) * 64 + ch) * 36 + wq * 8;
        *(uint4*)dst = make_uint4(ow[0], ow[1], ow[2], ow[3]);
        *(uint4*)(dst + 4) = make_uint4(ow[4], ow[5], ow[6], ow[7]);
    }
}

// K3: D^T = x1v^T @ A (A symmetric 0/1 from bitmask, in-register B-frags);
// epilogue W2 @ (di*D^T) via 2nd MFMA; relu+rowsum -> atomic gsum.
// 512 blocks (bt = blk&127 for XCD locality, rowblk = blk>>7), 256 thr.
__global__ __launch_bounds__(256) void k3_mfma(const void* __restrict__ pts,
                                               const void* __restrict__ W2,
                                               const void* __restrict__ b2,
                                               const float* __restrict__ dinv,
                                               const u32* __restrict__ bm,
                                               const u32* __restrict__ x1vB,
                                               float* __restrict__ gsum) {
    // pool dwords: sbm[0,8192) xf0[8192,10496) xf1[10496,12800) W2B[12800,15104)
    // sdi[15104,15360) sb2[15360,15424). dump overlays [0,9216) post-K-loop.
    __shared__ u32 pool[15424];
    __shared__ int s_flag;
    float* poolf = (float*)pool;
    int tid = threadIdx.x, lane = tid & 63, w = tid >> 6;
    int l15 = lane & 15, quad = lane >> 4;
    int blk = blockIdx.x, bt = blk & 127, rowblk = blk >> 7;
    bool bf = detect_bf16(pts, tid, &s_flag);

    const u32* xg = x1vB + (size_t)bt * 36864;   // 16 tiles * 2304 dw
    for (int it = w; it < 9; it += 4)            // prefetch tile 0 -> xf0
        gload16(xg + it * 256 + lane * 4, pool + 8192 + it * 256 + lane * 4);

    const u32* bg_ = bm + (size_t)bt * 32768 + rowblk * 256;
    for (int idx = tid; idx < 8192; idx += 256) {
        int c = idx >> 8, r = idx & 255;
        pool[idx] = bg_[c * 1024 + r];
    }
    unsigned short* W2B = (unsigned short*)(pool + 12800);
    for (int idx = tid; idx < 4096; idx += 256) {
        int o = idx >> 6, c = idx & 63;
        W2B[o * 72 + c] = f2bf(ldf(W2, idx, bf));
    }
    if (tid < 256) poolf[15104 + tid] = dinv[bt * N_PTS + rowblk * 256 + tid];
    if (tid < 64)  poolf[15360 + tid] = ldf(b2, tid, bf);

    f32x4 acc[4][4];   // [rf(row16-block)][nb(ch16-block)]
#pragma unroll
    for (int rf = 0; rf < 4; rf++)
#pragma unroll
        for (int nb = 0; nb < 4; nb++)
#pragma unroll
            for (int r = 0; r < 4; r++) acc[rf][nb][r] = 0.0f;

    for (int t = 0; t < 16; t++) {
        __syncthreads();   // drains vmcnt -> current buf ready
        if (t + 1 < 16) {
            u32* dst = pool + ((t & 1) ? 8192 : 10496);
            const u32* src = xg + (t + 1) * 2304;
            for (int it = w; it < 9; it += 4)
                gload16(src + it * 256 + lane * 4, dst + it * 256 + lane * 4);
        }
        const unsigned short* xf = (const unsigned short*)(pool + ((t & 1) ? 10496 : 8192));
#pragma unroll
        for (int ks = 0; ks < 2; ks++) {
            short8_t bq[4];
#pragma unroll
            for (int rf = 0; rf < 4; rf++) {
                u32 mw = pool[(2 * t + ks) * 256 + w * 64 + rf * 16 + l15];
                u32 by = (mw >> (quad * 8)) & 0xFFu;
                short8_t v;
#pragma unroll
                for (int i2 = 0; i2 < 8; i2++)
                    v[i2] = (by & (1u << i2)) ? (short)0x3F80 : (short)0;
                bq[rf] = v;
            }
#pragma unroll
            for (int nb = 0; nb < 4; nb++) {
                short8_t af = *(const short8_t*)(xf + (nb * 16 + l15) * 72 + ks * 32 + quad * 8);
#pragma unroll
                for (int rf = 0; rf < 4; rf++)
                    acc[rf][nb] = __builtin_amdgcn_mfma_f32_16x16x32_bf16(af, bq[rf], acc[rf][nb], 0, 0, 0);
            }
        }
    }
    __syncthreads();

    // dump di*D^T as bf16 [256 rows][72 shorts] (pad rows, 2-way-free banks)
    u32* dump = pool;
#pragma unroll
    for (int rf = 0; rf < 4; rf++) {
        int rn = w * 64 + rf * 16 + l15;
        float di = poolf[15104 + rn];
#pragma unroll
        for (int nb = 0; nb < 4; nb++) {
            u32 lo = (u32)f2bf(acc[rf][nb][0] * di) | ((u32)f2bf(acc[rf][nb][1] * di) << 16);
            u32 hi = (u32)f2bf(acc[rf][nb][2] * di) | ((u32)f2bf(acc[rf][nb][3] * di) << 16);
            u32* dst = dump + rn * 36 + nb * 8 + quad * 2;
            dst[0] = lo; dst[1] = hi;
        }
    }
    __syncthreads();
    f32x4 xacc[4][4];  // [ob(o16-block)][rf]
#pragma unroll
    for (int ob = 0; ob < 4; ob++)
#pragma unroll
        for (int rf = 0; rf < 4; rf++)
#pragma unroll
            for (int r = 0; r < 4; r++) xacc[ob][rf][r] = 0.0f;
#pragma unroll
    for (int ks2 = 0; ks2 < 2; ks2++) {
        short8_t b2f[4];
#pragma unroll
        for (int rf = 0; rf < 4; rf++)
            b2f[rf] = *(const short8_t*)((const unsigned short*)dump +
                        (w * 64 + rf * 16 + l15) * 72 + ks2 * 32 + quad * 8);
#pragma unroll
        for (int ob = 0; ob < 4; ob++) {
            short8_t a2 = *(const short8_t*)(W2B + (ob * 16 + l15) * 72 + ks2 * 32 + quad * 8);
#pragma unroll
            for (int rf = 0; rf < 4; rf++)
                xacc[ob][rf] = __builtin_amdgcn_mfma_f32_16x16x32_bf16(a2, b2f[rf], xacc[ob][rf], 0, 0, 0);
        }
    }
#pragma unroll
    for (int ob = 0; ob < 4; ob++) {
#pragma unroll
        for (int r = 0; r < 4; r++) {
            int o = ob * 16 + quad * 4 + r;
            float bb = poolf[15360 + o];
            float s = 0.0f;
#pragma unroll
            for (int rf = 0; rf < 4; rf++) s += fmaxf(xacc[ob][rf][r] + bb, 0.0f);
            s += __shfl_down(s, 8, 16);
            s += __shfl_down(s, 4, 16);
            s += __shfl_down(s, 2, 16);
            s += __shfl_down(s, 1, 16);
            if (l15 == 0) atomicAdd(&gsum[bt * 64 + o], s);
        }
    }
}

// K4 v3: readlane-based. Broadcasts go through v_readlane (VALU) instead of
// uniform ds_read_b128 convoys (DS pipe was the R7 bottleneck: 192 b128/iter).
__global__ __launch_bounds__(768, 1) void k4_all(const void* __restrict__ pts,
                                                 const void* __restrict__ Wg,
                                                 const void* __restrict__ bg,
                                                 const void* __restrict__ Wih,
                                                 const void* __restrict__ Whh,
                                                 const void* __restrict__ bih,
                                                 const void* __restrict__ bhh,
                                                 const void* __restrict__ Wf,
                                                 const void* __restrict__ bf_,
                                                 const float* __restrict__ gsum,
                                                 float* __restrict__ out) {
    int b = blockIdx.x, tid = threadIdx.x;
    __shared__ float s_gi[32 * 384];   // 48 KB
    __shared__ float sWgT[64 * 65];    // 16.25 KB
    __shared__ float s_gm[2048];       // 8 KB
    __shared__ float s_x[2048];        // 8 KB
    __shared__ float s_part[768];      // 3 KB
    __shared__ float s_h[128];
    __shared__ int s_flag;
    bool bf = detect_bf16(pts, tid, &s_flag);
    for (int idx = tid; idx < 4096; idx += 768) {
        int o = idx >> 6, k = idx & 63;
        sWgT[k * 65 + o] = ldf(Wg, idx, bf);
    }
    for (int idx = tid; idx < 2048; idx += 768)
        s_gm[idx] = gsum[(size_t)b * 2048 + idx] * (1.0f / 1024.0f);
    if (tid < 128) s_h[tid] = 0.0f;
    __syncthreads();
    // x[t][c] = bg[c] + Wg[c,:] @ gm[t,:]
    for (int idx = tid; idx < 2048; idx += 768) {
        int t = idx >> 6, c = idx & 63;
        float s0 = ldf(bg, c, bf), s1 = 0.f, s2 = 0.f, s3 = 0.f;
        const float* gm = s_gm + t * 64;
#pragma unroll
        for (int k = 0; k < 64; k += 4) {
            s0 = fmaf(sWgT[k * 65 + c],       gm[k],     s0);
            s1 = fmaf(sWgT[(k + 1) * 65 + c], gm[k + 1], s1);
            s2 = fmaf(sWgT[(k + 2) * 65 + c], gm[k + 2], s2);
            s3 = fmaf(sWgT[(k + 3) * 65 + c], gm[k + 3], s3);
        }
        s_x[idx] = (s0 + s1) + (s2 + s3);
    }
    __syncthreads();
    int hi = (tid >= 384) ? 1 : 0;      // wave-uniform (384 = 6 waves)
    int r = tid - hi * 384;
    int lane = tid & 63;
    // gi[t][r] for t ≡ hi (mod 2); Wih row r in regs; x[t] broadcast via readlane
    {
        float wv[64];
        if (bf) {
#pragma unroll
            for (int k = 0; k < 64; k++) wv[k] = bfi(((const unsigned short*)Wih)[r * 64 + k]);
        } else {
            const float4* wr = (const float4*)Wih + r * 16;
#pragma unroll
            for (int qq = 0; qq < 16; qq++) {
                float4 v = wr[qq];
                wv[4*qq] = v.x; wv[4*qq+1] = v.y; wv[4*qq+2] = v.z; wv[4*qq+3] = v.w;
            }
        }
        float br = ldf(bih, r, bf);
        for (int t = hi; t < 32; t += 2) {
            float xv = s_x[t * 64 + lane];          // one ds_read_b32 per wave
            float s0 = br, s1 = 0.f, s2 = 0.f, s3 = 0.f;
#pragma unroll
            for (int k = 0; k < 64; k += 4) {
                s0 = fmaf(wv[k],     rdlane(xv, k),     s0);
                s1 = fmaf(wv[k + 1], rdlane(xv, k + 1), s1);
                s2 = fmaf(wv[k + 2], rdlane(xv, k + 2), s2);
                s3 = fmaf(wv[k + 3], rdlane(xv, k + 3), s3);
            }
            s_gi[t * 384 + r] = (s0 + s1) + (s2 + s3);
        }
    }
    // Whh half-row in regs (64 f32)
    float wh2[64];
    {
        int koff = hi * 64;
        if (bf) {
#pragma unroll
            for (int k = 0; k < 64; k++)
                wh2[k] = bfi(((const unsigned short*)Whh)[r * 128 + koff + k]);
        } else {
            const float4* wr = (const float4*)Whh + (r * 128 + koff) / 4;
#pragma unroll
            for (int qq = 0; qq < 16; qq++) {
                float4 v = wr[qq];
                wh2[4*qq] = v.x; wh2[4*qq+1] = v.y; wh2[4*qq+2] = v.z; wh2[4*qq+3] = v.w;
            }
        }
    }
    float bhr = hi ? 0.0f : ldf(bhh, r, bf);
    float h_reg = 0.0f, hsum = 0.0f;
    __syncthreads();

    for (int t = 0; t < 32; t++) {
        float hval = s_h[hi * 64 + lane];           // one ds_read_b32 per wave
        float s0 = bhr, s1 = 0.f, s2 = 0.f, s3 = 0.f;
#pragma unroll
        for (int k = 0; k < 64; k += 4) {
            s0 = fmaf(wh2[k],     rdlane(hval, k),     s0);
            s1 = fmaf(wh2[k + 1], rdlane(hval, k + 1), s1);
            s2 = fmaf(wh2[k + 2], rdlane(hval, k + 2), s2);
            s3 = fmaf(wh2[k + 3], rdlane(hval, k + 3), s3);
        }
        s_part[tid] = (s0 + s1) + (s2 + s3);
        __syncthreads();
        if (tid < 128) {
            int c = tid;
            float gr = s_gi[t * 384 + c]       + s_part[c]       + s_part[384 + c];
            float gz = s_gi[t * 384 + 128 + c] + s_part[128 + c] + s_part[512 + c];
            float gn = s_gi[t * 384 + 256 + c];
            float hn = s_part[256 + c] + s_part[640 + c];
            float rr = 1.0f / (1.0f + expf(-gr));
            float z  = 1.0f / (1.0f + expf(-gz));
            float n  = tanhf(fmaf(rr, hn, gn));
            float hnew = (1.0f - z) * n + z * h_reg;
            h_reg = hnew; hsum += hnew; s_h[c] = hnew;
        }
        __syncthreads();
    }
    if (tid < 128) {
        float hm = hsum * (1.0f / 32.0f);
        s_part[tid]       = ldf(Wf, tid, bf) * hm;
        s_part[128 + tid] = ldf(Wf, 128 + tid, bf) * hm;
    }
    __syncthreads();
    if (tid < 2) {
        float s = ldf(bf_, tid, bf);
        for (int k = 0; k < 128; k++) s += s_part[tid * 128 + k];
        out[b * 2 + tid] = s;   // f32 output (verified R4)
    }
}

extern "C" void kernel_launch(void* const* d_in, const int* in_sizes, int n_in,
                              void* d_out, int out_size, void* d_ws, size_t ws_size,
                              hipStream_t stream) {
    const void* pts = d_in[0];
    const void* W1  = d_in[1];
    const void* b1  = d_in[2];
    const void* W2  = d_in[3];
    const void* b2  = d_in[4];
    const void* Wg  = d_in[5];
    const void* bg  = d_in[6];
    const void* Wih = d_in[7];
    const void* Whh = d_in[8];
    const void* bih = d_in[9];
    const void* bhh = d_in[10];
    const void* Wf  = d_in[11];
    const void* bf_ = d_in[12];

    // ws: dinv 512K | gsum 32K | bm 16M | x1vB 18M  (~34.5 MB)
    float* dinv = (float*)d_ws;
    float* gsum = dinv + (size_t)BT * N_PTS;
    u32*   bm   = (u32*)(gsum + BT * 64);
    u32*   x1vB = bm + (size_t)BT * 32768;

    k1_bm  <<<512, 256, 0, stream>>>(pts, dinv, gsum, bm);
    k2_x1v <<<512, 256, 0, stream>>>(pts, W1, b1, dinv, bm, x1vB);
    k3_mfma<<<512, 256, 0, stream>>>(pts, W2, b2, dinv, bm, x1vB, gsum);
    k4_all <<<4, 768, 0, stream>>>(pts, Wg, bg, Wih, Whh, bih, bhh, Wf, bf_,
                                   gsum, (float*)d_out);
}